// Round 1
// baseline (5103.226 us; speedup 1.0000x reference)
//
#include <hip/hip_runtime.h>

#define DEVI __device__ __forceinline__

typedef __attribute__((ext_vector_type(8)))  short short8;
typedef __attribute__((ext_vector_type(4)))  short short4v;
typedef __attribute__((ext_vector_type(16))) float f32x16;

// ---- problem dims ----
constexpr int NROW = 8192;
constexpr int HD   = 512;
constexpr int DIN  = 256;
constexpr int NC   = 10;

// ---- tiling ----
constexpr int NP  = 22;   // gate/up pair tiles: 682 padded to 704 = 22*32
constexpr int KT1 = 32;   // GEMM1 K = 512 / 16
constexpr int KT2 = 44;   // GEMM2 K = 704 / 16
constexpr int KTX = 16;   // x_proj K = 256 / 16
constexpr int NTH = 16;   // H-wide outputs: 512 / 32

constexpr int SZ_GU = KT1*NP*64*8;    // 360448 elems per gate/up frag tensor
constexpr int SZ_D  = KT2*NTH*64*8;   // 360448
constexpr int SZ_IN = KTX*NTH*64*8;   // 131072

DEVI short f2bf(float x){
  unsigned u = __builtin_bit_cast(unsigned, x);
  unsigned r = u + 0x7FFFu + ((u >> 16) & 1u);
  return (short)(r >> 16);
}
DEVI float bf2f(short s){
  unsigned u = ((unsigned)(unsigned short)s) << 16;
  return __builtin_bit_cast(float, u);
}
DEVI f32x16 MF(short8 a, short8 b, f32x16 c){
  return __builtin_amdgcn_mfma_f32_32x32x16_bf16(a, b, c, 0, 0, 0);
}
DEVI f32x16 fzero(){
  f32x16 v;
  #pragma unroll
  for (int i = 0; i < 16; ++i) v[i] = 0.f;
  return v;
}

struct WSet { const short *GH, *GL, *UH, *UL, *DH, *DL; };

// store silu(gate)*up for one 32-col pair into inter frag buffers (hi/lo bf16)
DEVI void silu_store(int p, const f32x16& cg, const f32x16& cu,
                     short* INh_, short* INl_, int l)
{
  const int m = l & 31, g = l >> 5;
  #pragma unroll
  for (int q = 0; q < 4; ++q) {
    short4v hi, lo;
    #pragma unroll
    for (int pos = 0; pos < 4; ++pos) {
      const int r = q*4 + pos;
      float gv = cg[r], uv = cu[r];
      float sv = (gv / (1.0f + __expf(-gv))) * uv;   // silu(g)*u
      short h = f2bf(sv);
      hi[pos] = h;
      lo[pos] = f2bf(sv - bf2f(h));
    }
    const int kt2  = 2*p + (q >> 1);
    const int slot = ((q & 1) << 5) + m;
    const int base = (kt2*64 + slot)*8 + (g << 2);
    *(short4v*)&INh_[base] = hi;
    *(short4v*)&INl_[base] = lo;
  }
}

// GEMM1 pass over NPAIR (gate,up) 32-col pairs: p = p0 + 8*j
template<int NPAIR>
DEVI void g1pass(int p0, const WSet& Wt,
                 const short* A1h_, const short* A1l_,
                 short* INh_, short* INl_, int l)
{
  f32x16 ag[NPAIR], au[NPAIR];
  #pragma unroll
  for (int j = 0; j < NPAIR; ++j) { ag[j] = fzero(); au[j] = fzero(); }
  const short *pGH[NPAIR], *pGL[NPAIR], *pUH[NPAIR], *pUL[NPAIR];
  #pragma unroll
  for (int j = 0; j < NPAIR; ++j) {
    const int p = p0 + 8*j;
    pGH[j] = Wt.GH + p*512 + l*8;
    pGL[j] = Wt.GL + p*512 + l*8;
    pUH[j] = Wt.UH + p*512 + l*8;
    pUL[j] = Wt.UL + p*512 + l*8;
  }
  #pragma unroll 2
  for (int kt = 0; kt < KT1; ++kt) {
    const int ab = (kt*64 + l)*8;
    short8 bh = *(const short8*)&A1h_[ab];
    short8 bl = *(const short8*)&A1l_[ab];
    const int o = kt*(NP*512);
    #pragma unroll
    for (int j = 0; j < NPAIR; ++j) {
      short8 gh = *(const short8*)(pGH[j] + o);
      short8 gl = *(const short8*)(pGL[j] + o);
      short8 uh = *(const short8*)(pUH[j] + o);
      short8 ul = *(const short8*)(pUL[j] + o);
      ag[j] = MF(gh, bh, ag[j]);
      ag[j] = MF(gl, bh, ag[j]);
      ag[j] = MF(gh, bl, ag[j]);
      au[j] = MF(uh, bh, au[j]);
      au[j] = MF(ul, bh, au[j]);
      au[j] = MF(uh, bl, au[j]);
    }
  }
  #pragma unroll
  for (int j = 0; j < NPAIR; ++j)
    silu_store(p0 + 8*j, ag[j], au[j], INh_, INl_, l);
}

// one SwiGLU sublayer + residual + rmsnorm, in-place on register state S[32]
DEVI void sublayer(float (&S)[32], const WSet& Wt,
                   short* A1h_, short* A1l_, short* INh_, short* INl_,
                   float* rmsS_, int w, int l)
{
  const int m = l & 31, g = l >> 5;
  // ---- stage h0 fragments (hi/lo) into LDS ----
  #pragma unroll
  for (int t = 0; t < 2; ++t) {
    #pragma unroll
    for (int q = 0; q < 4; ++q) {
      short4v hi, lo;
      #pragma unroll
      for (int pos = 0; pos < 4; ++pos) {
        float v = S[t*16 + q*4 + pos];
        short h = f2bf(v);
        hi[pos] = h;
        lo[pos] = f2bf(v - bf2f(h));
      }
      const int kt   = 4*w + 2*t + (q >> 1);
      const int slot = ((q & 1) << 5) + m;
      const int base = (kt*64 + slot)*8 + (g << 2);
      *(short4v*)&A1h_[base] = hi;
      *(short4v*)&A1l_[base] = lo;
    }
  }
  __syncthreads();
  // ---- GEMM1 (transposed: weights are A, h0 frags are B) + silu ----
  g1pass<2>(w, Wt, A1h_, A1l_, INh_, INl_, l);
  if (w + 16 < NP) g1pass<1>(w + 16, Wt, A1h_, A1l_, INh_, INl_, l);
  __syncthreads();
  // ---- GEMM2 ----
  f32x16 c0 = fzero(), c1 = fzero();
  {
    const short* d0h = Wt.DH + (2*w  )*512 + l*8;
    const short* d0l = Wt.DL + (2*w  )*512 + l*8;
    const short* d1h = Wt.DH + (2*w+1)*512 + l*8;
    const short* d1l = Wt.DL + (2*w+1)*512 + l*8;
    #pragma unroll 2
    for (int kt = 0; kt < KT2; ++kt) {
      const int ab = (kt*64 + l)*8;
      short8 bh = *(const short8*)&INh_[ab];
      short8 bl = *(const short8*)&INl_[ab];
      const int o = kt*(NTH*512);
      short8 a0h = *(const short8*)(d0h + o);
      short8 a0l = *(const short8*)(d0l + o);
      short8 a1h = *(const short8*)(d1h + o);
      short8 a1l = *(const short8*)(d1l + o);
      c0 = MF(a0h, bh, c0); c0 = MF(a0l, bh, c0); c0 = MF(a0h, bl, c0);
      c1 = MF(a1h, bh, c1); c1 = MF(a1l, bh, c1); c1 = MF(a1h, bl, c1);
    }
  }
  // ---- residual + rmsnorm (thread-local: C^T frags align with state) ----
  float ss = 0.f;
  #pragma unroll
  for (int s = 0; s < 32; ++s) {
    float y = S[s] + (s < 16 ? c0[s & 15] : c1[s & 15]);
    S[s] = y;
    ss += y*y;
  }
  ss += __shfl_xor(ss, 32);
  if (l < 32) rmsS_[w*32 + l] = ss;
  __syncthreads();
  float tot = 0.f;
  #pragma unroll
  for (int wv = 0; wv < 8; ++wv) tot += rmsS_[wv*32 + m];
  const float rinv = 1.0f / sqrtf(tot * (1.0f/512.0f) + 1e-6f);
  #pragma unroll
  for (int s = 0; s < 32; ++s) S[s] *= rinv;
}

__global__ __launch_bounds__(512, 2) void trm_main(
    const float* __restrict__ x,
    const float* __restrict__ b_in,
    const float* __restrict__ W_fb,
    const float* __restrict__ b_fb,
    const float* __restrict__ H_init,
    const float* __restrict__ L_init,
    const float* __restrict__ W_out,
    const float* __restrict__ b_out,
    float* __restrict__ xp,
    const short* __restrict__ BinH, const short* __restrict__ BinL,
    const short* __restrict__ G1H, const short* __restrict__ G1L,
    const short* __restrict__ U1H, const short* __restrict__ U1L,
    const short* __restrict__ D1H, const short* __restrict__ D1L,
    const short* __restrict__ G2H, const short* __restrict__ G2L,
    const short* __restrict__ U2H, const short* __restrict__ U2L,
    const short* __restrict__ D2H, const short* __restrict__ D2L,
    float* __restrict__ out)
{
  __shared__ alignas(16) char smem[156672];
  short* A1h  = (short*)(smem);            // [32][64][8] bf16-hi h0 frags (32KB)
  short* A1l  = (short*)(smem + 32768);    // lo (32KB)
  short* INh  = (short*)(smem + 65536);    // [44][64][8] inter hi (45KB)
  short* INl  = (short*)(smem + 110592);   // lo (45KB)
  float* rmsS = (float*)(smem + 155648);   // [8][32]
  float* lgS  = (float*)(smem);            // k-epilogue alias over A1 region
  float* pbS  = (float*)(smem + 10240);

  const int tid = threadIdx.x;
  const int l = tid & 63;
  const int w = tid >> 6;
  const int m = l & 31;
  const int g = l >> 5;
  const int wg = blockIdx.x;
  const int row0 = wg * 32;

  float zL[32], zH[32], cb[32];

  // ================= x_proj = x @ W_in + b_in =================
  #pragma unroll
  for (int kk = 0; kk < 2; ++kk) {
    const int kt = 2*w + kk;
    const float4* xr = (const float4*)(x + (size_t)(row0 + m)*DIN + kt*16 + g*8);
    float4 v0 = xr[0];
    float4 v1 = xr[1];
    float v[8] = {v0.x, v0.y, v0.z, v0.w, v1.x, v1.y, v1.z, v1.w};
    short8 hi, lo;
    #pragma unroll
    for (int i = 0; i < 8; ++i) {
      short h = f2bf(v[i]);
      hi[i] = h;
      lo[i] = f2bf(v[i] - bf2f(h));
    }
    const int base = (kt*64 + l)*8;
    *(short8*)&A1h[base] = hi;
    *(short8*)&A1l[base] = lo;
  }
  __syncthreads();
  {
    f32x16 c0 = fzero(), c1 = fzero();
    const short* i0h = BinH + (2*w  )*512 + l*8;
    const short* i0l = BinL + (2*w  )*512 + l*8;
    const short* i1h = BinH + (2*w+1)*512 + l*8;
    const short* i1l = BinL + (2*w+1)*512 + l*8;
    #pragma unroll 2
    for (int kt = 0; kt < KTX; ++kt) {
      const int ab = (kt*64 + l)*8;
      short8 bh = *(const short8*)&A1h[ab];
      short8 bl = *(const short8*)&A1l[ab];
      const int o = kt*(NTH*512);
      short8 a0h = *(const short8*)(i0h + o);
      short8 a0l = *(const short8*)(i0l + o);
      short8 a1h = *(const short8*)(i1h + o);
      short8 a1l = *(const short8*)(i1l + o);
      c0 = MF(a0h, bh, c0); c0 = MF(a0l, bh, c0); c0 = MF(a0h, bl, c0);
      c1 = MF(a1h, bh, c1); c1 = MF(a1l, bh, c1); c1 = MF(a1h, bl, c1);
    }
    #pragma unroll
    for (int s = 0; s < 32; ++s) {
      const int r = s & 15;
      const int cc = w*64 + (s >> 4)*32 + (r & 3) + ((r >> 2) << 3) + (g << 2);
      float v = (s < 16 ? c0[r] : c1[r]) + b_in[cc];
      cb[s] = v;
      xp[(size_t)(wg*8 + w)*2048 + s*64 + l] = v;
      zH[s] = H_init[cc];
      zL[s] = L_init[cc];
    }
  }
  __syncthreads();

  const WSet W1{G1H, G1L, U1H, U1L, D1H, D1L};
  const WSet W2{G2H, G2L, U2H, U2L, D2H, D2L};

  #pragma unroll 1
  for (int k = 0; k < 4; ++k) {
    #pragma unroll 1
    for (int hc = 0; hc < 2; ++hc) {
      #pragma unroll 1
      for (int li = 0; li < 3; ++li) {
        #pragma unroll
        for (int s = 0; s < 32; ++s) zL[s] += zH[s] + cb[s];
        #pragma unroll 1
        for (int sub = 0; sub < 2; ++sub)
          sublayer(zL, sub ? W2 : W1, A1h, A1l, INh, INl, rmsS, w, l);
      }
      #pragma unroll
      for (int s = 0; s < 32; ++s) zH[s] += zL[s];
      #pragma unroll 1
      for (int sub = 0; sub < 2; ++sub)
        sublayer(zH, sub ? W2 : W1, A1h, A1l, INh, INl, rmsS, w, l);
    }
    // ================= k-epilogue: logits / softmax / feedback =================
    {
      float part[10];
      #pragma unroll
      for (int c = 0; c < NC; ++c) part[c] = 0.f;
      #pragma unroll
      for (int s = 0; s < 32; ++s) {
        const int r = s & 15;
        const int cc = w*64 + (s >> 4)*32 + (r & 3) + ((r >> 2) << 3) + (g << 2);
        const float zz = zH[s];
        #pragma unroll
        for (int c = 0; c < NC; ++c) part[c] += zz * W_out[cc*NC + c];
      }
      #pragma unroll
      for (int c = 0; c < NC; ++c) part[c] += __shfl_xor(part[c], 32);
      if (l < 32) {
        #pragma unroll
        for (int c = 0; c < NC; ++c) lgS[(w*32 + l)*NC + c] = part[c];
      }
      __syncthreads();
      if (w == 0 && l < 32) {
        float lg[10];
        #pragma unroll
        for (int c = 0; c < NC; ++c) lg[c] = b_out[c];
        #pragma unroll
        for (int wv = 0; wv < 8; ++wv) {
          #pragma unroll
          for (int c = 0; c < NC; ++c) lg[c] += lgS[(wv*32 + l)*NC + c];
        }
        const int row = row0 + l;
        #pragma unroll
        for (int c = 0; c < NC; ++c) out[(size_t)(1 + k)*81920 + row*NC + c] = lg[c];
        if (k == 3) {
          #pragma unroll
          for (int c = 0; c < NC; ++c) out[row*NC + c] = lg[c];
        }
        float mx = lg[0];
        #pragma unroll
        for (int c = 1; c < NC; ++c) mx = fmaxf(mx, lg[c]);
        float e[10], sum = 0.f;
        #pragma unroll
        for (int c = 0; c < NC; ++c) { e[c] = __expf(lg[c] - mx); sum += e[c]; }
        const float inv = 1.0f / sum;
        #pragma unroll
        for (int c = 0; c < NC; ++c) pbS[l*NC + c] = e[c] * inv;
      }
      __syncthreads();
      if (k < 3) {
        #pragma unroll
        for (int s = 0; s < 32; ++s) {
          const int r = s & 15;
          const int cc = w*64 + (s >> 4)*32 + (r & 3) + ((r >> 2) << 3) + (g << 2);
          float fb = b_fb[cc];
          #pragma unroll
          for (int c = 0; c < NC; ++c) fb += pbS[m*NC + c] * W_fb[c*HD + cc];
          cb[s] = xp[(size_t)(wg*8 + w)*2048 + s*64 + l] + fb;
        }
      }
      __syncthreads();   // protect lgS/pbS (A1 alias) before next A1 staging
    }
  }
}

// ===================== weight preprocessing =====================
__global__ void prep_gu(const float* __restrict__ Wgu,
                        short* __restrict__ GH, short* __restrict__ GL,
                        short* __restrict__ UH, short* __restrict__ UL)
{
  const int t = blockIdx.x*256 + threadIdx.x;
  if (t >= 2*KT1*NP*64) return;
  const int l = t & 63;
  const int rest = t >> 6;
  const int nt = rest % NP;
  const int rest2 = rest / NP;
  const int kt = rest2 & 31;
  const int gu = rest2 >> 5;
  const int n  = nt*32 + (l & 31);
  const int kb = kt*16 + (l >> 5)*8;
  short8 hi, lo;
  #pragma unroll
  for (int i = 0; i < 8; ++i) {
    float v = 0.f;
    if (n < 682) v = Wgu[(size_t)(kb + i)*1364 + gu*682 + n];
    short h = f2bf(v);
    hi[i] = h;
    lo[i] = f2bf(v - bf2f(h));
  }
  const int base = ((kt*NP + nt)*64 + l)*8;
  short* H = gu ? UH : GH;
  short* L = gu ? UL : GL;
  *(short8*)&H[base] = hi;
  *(short8*)&L[base] = lo;
}

__global__ void prep_d(const float* __restrict__ Wd,
                       short* __restrict__ DH, short* __restrict__ DL)
{
  const int t = blockIdx.x*256 + threadIdx.x;
  if (t >= KT2*NTH*64) return;
  const int l = t & 63;
  const int rest = t >> 6;
  const int nt = rest % NTH;
  const int kt2 = rest / NTH;
  const int n  = nt*32 + (l & 31);
  const int kb = kt2*16 + (l >> 5)*8;
  short8 hi, lo;
  #pragma unroll
  for (int i = 0; i < 8; ++i) {
    const int k2 = kb + i;
    float v = (k2 < 682) ? Wd[(size_t)k2*HD + n] : 0.f;
    short h = f2bf(v);
    hi[i] = h;
    lo[i] = f2bf(v - bf2f(h));
  }
  const int base = ((kt2*NTH + nt)*64 + l)*8;
  *(short8*)&DH[base] = hi;
  *(short8*)&DL[base] = lo;
}

__global__ void prep_in(const float* __restrict__ Win,
                        short* __restrict__ IH, short* __restrict__ IL)
{
  const int t = blockIdx.x*256 + threadIdx.x;
  if (t >= KTX*NTH*64) return;
  const int l = t & 63;
  const int rest = t >> 6;
  const int nt = rest % NTH;
  const int kt = rest / NTH;
  const int n  = nt*32 + (l & 31);
  const int kb = kt*16 + (l >> 5)*8;
  short8 hi, lo;
  #pragma unroll
  for (int i = 0; i < 8; ++i) {
    float v = Win[(size_t)(kb + i)*HD + n];
    short h = f2bf(v);
    hi[i] = h;
    lo[i] = f2bf(v - bf2f(h));
  }
  const int base = ((kt*NTH + nt)*64 + l)*8;
  *(short8*)&IH[base] = hi;
  *(short8*)&IL[base] = lo;
}

extern "C" void kernel_launch(void* const* d_in, const int* in_sizes, int n_in,
                              void* d_out, int out_size, void* d_ws, size_t ws_size,
                              hipStream_t stream)
{
  const float* x     = (const float*)d_in[0];
  const float* W_in  = (const float*)d_in[1];
  const float* b_in  = (const float*)d_in[2];
  const float* W_fb  = (const float*)d_in[3];
  const float* b_fb  = (const float*)d_in[4];
  const float* Wgu1  = (const float*)d_in[5];
  const float* Wd1   = (const float*)d_in[6];
  const float* Wgu2  = (const float*)d_in[7];
  const float* Wd2   = (const float*)d_in[8];
  const float* Hini  = (const float*)d_in[9];
  const float* Lini  = (const float*)d_in[10];
  const float* W_out = (const float*)d_in[11];
  const float* b_out = (const float*)d_in[12];
  float* out = (float*)d_out;

  char* ws = (char*)d_ws;
  size_t off = 0;
  auto alloc = [&](size_t bytes) {
    char* p = ws + off;
    off = (off + bytes + 255) & ~(size_t)255;
    return p;
  };
  float* xp   = (float*)alloc((size_t)NROW*HD*4);
  short* BinH = (short*)alloc((size_t)SZ_IN*2);
  short* BinL = (short*)alloc((size_t)SZ_IN*2);
  short* G1H = (short*)alloc((size_t)SZ_GU*2); short* G1L = (short*)alloc((size_t)SZ_GU*2);
  short* U1H = (short*)alloc((size_t)SZ_GU*2); short* U1L = (short*)alloc((size_t)SZ_GU*2);
  short* D1H = (short*)alloc((size_t)SZ_D*2);  short* D1L = (short*)alloc((size_t)SZ_D*2);
  short* G2H = (short*)alloc((size_t)SZ_GU*2); short* G2L = (short*)alloc((size_t)SZ_GU*2);
  short* U2H = (short*)alloc((size_t)SZ_GU*2); short* U2L = (short*)alloc((size_t)SZ_GU*2);
  short* D2H = (short*)alloc((size_t)SZ_D*2);  short* D2L = (short*)alloc((size_t)SZ_D*2);

  const int n1 = 2*KT1*NP*64;
  prep_gu<<<(n1+255)/256, 256, 0, stream>>>(Wgu1, G1H, G1L, U1H, U1L);
  prep_gu<<<(n1+255)/256, 256, 0, stream>>>(Wgu2, G2H, G2L, U2H, U2L);
  const int n2 = KT2*NTH*64;
  prep_d<<<(n2+255)/256, 256, 0, stream>>>(Wd1, D1H, D1L);
  prep_d<<<(n2+255)/256, 256, 0, stream>>>(Wd2, D2H, D2L);
  const int n3 = KTX*NTH*64;
  prep_in<<<(n3+255)/256, 256, 0, stream>>>(W_in, BinH, BinL);

  trm_main<<<256, 512, 0, stream>>>(x, b_in, W_fb, b_fb, Hini, Lini, W_out, b_out,
      xp, BinH, BinL,
      G1H, G1L, U1H, U1L, D1H, D1L,
      G2H, G2L, U2H, U2L, D2H, D2L,
      out);
}

// Round 2
// 4708.505 us; speedup vs baseline: 1.0838x; 1.0838x over previous
//
#include <hip/hip_runtime.h>

#define DEVI __device__ __forceinline__

typedef __attribute__((ext_vector_type(8)))  short short8;
typedef __attribute__((ext_vector_type(4)))  short short4v;
typedef __attribute__((ext_vector_type(16))) float f32x16;

// ---- problem dims ----
constexpr int NROW = 8192;
constexpr int HD   = 512;
constexpr int DIN  = 256;
constexpr int NC   = 10;

// ---- tiling ----
constexpr int NP  = 22;   // gate/up pair tiles: 682 padded to 704 = 22*32
constexpr int KT1 = 32;   // GEMM1 K = 512 / 16
constexpr int KT2 = 44;   // GEMM2 K = 704 / 16
constexpr int KTX = 16;   // x_proj K = 256 / 16
constexpr int NTH = 16;   // H-wide outputs: 512 / 32

// packed weight tensor sizes (shorts)
constexpr int SZ_P1  = KT1*NP*64*32;   // GEMM1: [gh8,gl8,uh8,ul8] per lane per (kt,nt)
constexpr int SZ_PD  = KT2*NTH*64*16;  // GEMM2: [dh8,dl8]
constexpr int SZ_PIN = KTX*NTH*64*16;  // x_proj: [ih8,il8]

DEVI short f2bf(float x){
  unsigned u = __builtin_bit_cast(unsigned, x);
  unsigned r = u + 0x7FFFu + ((u >> 16) & 1u);
  return (short)(r >> 16);
}
DEVI float bf2f(short s){
  unsigned u = ((unsigned)(unsigned short)s) << 16;
  return __builtin_bit_cast(float, u);
}
DEVI f32x16 MF(short8 a, short8 b, f32x16 c){
  return __builtin_amdgcn_mfma_f32_32x32x16_bf16(a, b, c, 0, 0, 0);
}
DEVI f32x16 fzero(){
  f32x16 v;
  #pragma unroll
  for (int i = 0; i < 16; ++i) v[i] = 0.f;
  return v;
}

// store silu(gate)*up for one 32-col pair into inter frag buffers (hi/lo bf16)
DEVI void silu_store(int p, const f32x16& cg, const f32x16& cu,
                     short* INh_, short* INl_, int l)
{
  const int m = l & 31, g = l >> 5;
  #pragma unroll
  for (int q = 0; q < 4; ++q) {
    short4v hi, lo;
    #pragma unroll
    for (int pos = 0; pos < 4; ++pos) {
      const int r = q*4 + pos;
      float gv = cg[r], uv = cu[r];
      float sv = (gv / (1.0f + __expf(-gv))) * uv;   // silu(g)*u
      short h = f2bf(sv);
      hi[pos] = h;
      lo[pos] = f2bf(sv - bf2f(h));
    }
    const int kt2  = 2*p + (q >> 1);
    const int slot = ((q & 1) << 5) + m;
    const int base = (kt2*64 + slot)*8 + (g << 2);
    *(short4v*)&INh_[base] = hi;
    *(short4v*)&INl_[base] = lo;
  }
}

// GEMM1: packed weights, 1-stage register prefetch pipeline.
// pair p = w + 8*j, j in [0,NPAIR)
template<int NPAIR>
DEVI void g1(const short* __restrict__ PW, int w, int l,
             const short* __restrict__ A1h_, const short* __restrict__ A1l_,
             short* __restrict__ INh_, short* __restrict__ INl_)
{
  constexpr int KSTR = NP*64*32;   // shorts per kt step
  f32x16 ag[NPAIR], au[NPAIR];
  #pragma unroll
  for (int j = 0; j < NPAIR; ++j) { ag[j] = fzero(); au[j] = fzero(); }
  const short* base[NPAIR];
  #pragma unroll
  for (int j = 0; j < NPAIR; ++j)
    base[j] = PW + ((size_t)((w + 8*j)*64 + l))*32;

  short8 wa[NPAIR][4], wb[NPAIR][4];
  #pragma unroll
  for (int j = 0; j < NPAIR; ++j) {
    #pragma unroll
    for (int i = 0; i < 4; ++i)
      wa[j][i] = *(const short8*)(base[j] + i*8);
  }

  #pragma unroll 1
  for (int kt = 0; kt < KT1; kt += 2) {
    short8 bh0 = *(const short8*)&A1h_[(kt*64 + l)*8];
    short8 bl0 = *(const short8*)&A1l_[(kt*64 + l)*8];
    #pragma unroll
    for (int j = 0; j < NPAIR; ++j) {
      const short* p = base[j] + (size_t)(kt + 1)*KSTR;
      #pragma unroll
      for (int i = 0; i < 4; ++i) wb[j][i] = *(const short8*)(p + i*8);
    }
    #pragma unroll
    for (int j = 0; j < NPAIR; ++j) {
      ag[j] = MF(wa[j][0], bh0, ag[j]);
      ag[j] = MF(wa[j][1], bh0, ag[j]);
      ag[j] = MF(wa[j][0], bl0, ag[j]);
      au[j] = MF(wa[j][2], bh0, au[j]);
      au[j] = MF(wa[j][3], bh0, au[j]);
      au[j] = MF(wa[j][2], bl0, au[j]);
    }
    short8 bh1 = *(const short8*)&A1h_[((kt+1)*64 + l)*8];
    short8 bl1 = *(const short8*)&A1l_[((kt+1)*64 + l)*8];
    if (kt + 2 < KT1) {
      #pragma unroll
      for (int j = 0; j < NPAIR; ++j) {
        const short* p = base[j] + (size_t)(kt + 2)*KSTR;
        #pragma unroll
        for (int i = 0; i < 4; ++i) wa[j][i] = *(const short8*)(p + i*8);
      }
    }
    #pragma unroll
    for (int j = 0; j < NPAIR; ++j) {
      ag[j] = MF(wb[j][0], bh1, ag[j]);
      ag[j] = MF(wb[j][1], bh1, ag[j]);
      ag[j] = MF(wb[j][0], bl1, ag[j]);
      au[j] = MF(wb[j][2], bh1, au[j]);
      au[j] = MF(wb[j][3], bh1, au[j]);
      au[j] = MF(wb[j][2], bl1, au[j]);
    }
  }
  #pragma unroll
  for (int j = 0; j < NPAIR; ++j)
    silu_store(w + 8*j, ag[j], au[j], INh_, INl_, l);
}

// one SwiGLU sublayer + residual + rmsnorm, in-place on register state S[32]
DEVI void sublayer(float (&S)[32], const short* __restrict__ PW, const short* __restrict__ PD,
                   short* A1h_, short* A1l_, short* INh_, short* INl_,
                   float* rmsS_, int w, int l)
{
  const int m = l & 31, g = l >> 5;
  // ---- stage h0 fragments (hi/lo) into LDS ----
  #pragma unroll
  for (int t = 0; t < 2; ++t) {
    #pragma unroll
    for (int q = 0; q < 4; ++q) {
      short4v hi, lo;
      #pragma unroll
      for (int pos = 0; pos < 4; ++pos) {
        float v = S[t*16 + q*4 + pos];
        short h = f2bf(v);
        hi[pos] = h;
        lo[pos] = f2bf(v - bf2f(h));
      }
      const int kt   = 4*w + 2*t + (q >> 1);
      const int slot = ((q & 1) << 5) + m;
      const int base = (kt*64 + slot)*8 + (g << 2);
      *(short4v*)&A1h_[base] = hi;
      *(short4v*)&A1l_[base] = lo;
    }
  }
  __syncthreads();
  // ---- GEMM1 (transposed: weights are A, h0 frags are B) + silu ----
  if (w < 6) g1<3>(PW, w, l, A1h_, A1l_, INh_, INl_);
  else       g1<2>(PW, w, l, A1h_, A1l_, INh_, INl_);
  __syncthreads();
  // ---- GEMM2 (packed [dh,dl], 1-stage prefetch) ----
  f32x16 c0 = fzero(), c1 = fzero();
  {
    constexpr int DSTR = NTH*64*16;   // shorts per kt2 step
    const short* bD = PD + ((size_t)(2*w*64 + l))*16;
    short8 da0 = *(const short8*)(bD);
    short8 da1 = *(const short8*)(bD + 8);
    short8 da2 = *(const short8*)(bD + 1024);
    short8 da3 = *(const short8*)(bD + 1032);
    short8 db0, db1, db2, db3;
    #pragma unroll 1
    for (int kt = 0; kt < KT2; kt += 2) {
      short8 bh0 = *(const short8*)&INh_[(kt*64 + l)*8];
      short8 bl0 = *(const short8*)&INl_[(kt*64 + l)*8];
      {
        const short* p = bD + (size_t)(kt + 1)*DSTR;
        db0 = *(const short8*)(p);
        db1 = *(const short8*)(p + 8);
        db2 = *(const short8*)(p + 1024);
        db3 = *(const short8*)(p + 1032);
      }
      c0 = MF(da0, bh0, c0); c0 = MF(da1, bh0, c0); c0 = MF(da0, bl0, c0);
      c1 = MF(da2, bh0, c1); c1 = MF(da3, bh0, c1); c1 = MF(da2, bl0, c1);
      short8 bh1 = *(const short8*)&INh_[((kt+1)*64 + l)*8];
      short8 bl1 = *(const short8*)&INl_[((kt+1)*64 + l)*8];
      if (kt + 2 < KT2) {
        const short* p = bD + (size_t)(kt + 2)*DSTR;
        da0 = *(const short8*)(p);
        da1 = *(const short8*)(p + 8);
        da2 = *(const short8*)(p + 1024);
        da3 = *(const short8*)(p + 1032);
      }
      c0 = MF(db0, bh1, c0); c0 = MF(db1, bh1, c0); c0 = MF(db0, bl1, c0);
      c1 = MF(db2, bh1, c1); c1 = MF(db3, bh1, c1); c1 = MF(db2, bl1, c1);
    }
  }
  // ---- residual + rmsnorm (thread-local: C^T frags align with state) ----
  float ss = 0.f;
  #pragma unroll
  for (int s = 0; s < 32; ++s) {
    float y = S[s] + (s < 16 ? c0[s & 15] : c1[s & 15]);
    S[s] = y;
    ss += y*y;
  }
  ss += __shfl_xor(ss, 32);
  if (l < 32) rmsS_[w*32 + l] = ss;
  __syncthreads();
  float tot = 0.f;
  #pragma unroll
  for (int wv = 0; wv < 8; ++wv) tot += rmsS_[wv*32 + m];
  const float rinv = 1.0f / sqrtf(tot * (1.0f/512.0f) + 1e-6f);
  #pragma unroll
  for (int s = 0; s < 32; ++s) S[s] *= rinv;
}

__global__ __launch_bounds__(512, 2) void trm_main(
    const float* __restrict__ x,
    const float* __restrict__ b_in,
    const float* __restrict__ W_fb,
    const float* __restrict__ b_fb,
    const float* __restrict__ H_init,
    const float* __restrict__ L_init,
    const float* __restrict__ W_out,
    const float* __restrict__ b_out,
    float* __restrict__ xp,
    const short* __restrict__ PIN,
    const short* __restrict__ P1, const short* __restrict__ PD1,
    const short* __restrict__ P2, const short* __restrict__ PD2,
    float* __restrict__ out)
{
  __shared__ alignas(16) char smem[156672];
  short* A1h  = (short*)(smem);            // [32][64][8] bf16-hi h0 frags (32KB)
  short* A1l  = (short*)(smem + 32768);    // lo (32KB)
  short* INh  = (short*)(smem + 65536);    // [44][64][8] inter hi (45KB)
  short* INl  = (short*)(smem + 110592);   // lo (45KB)
  float* rmsS = (float*)(smem + 155648);   // [8][32]
  float* lgS  = (float*)(smem);            // k-epilogue alias over A1 region
  float* pbS  = (float*)(smem + 10240);

  const int tid = threadIdx.x;
  const int l = tid & 63;
  const int w = tid >> 6;
  const int m = l & 31;
  const int g = l >> 5;
  const int wg = blockIdx.x;
  const int row0 = wg * 32;

  float zL[32], zH[32], cb[32];

  // ================= x_proj = x @ W_in + b_in =================
  #pragma unroll
  for (int kk = 0; kk < 2; ++kk) {
    const int kt = 2*w + kk;
    const float4* xr = (const float4*)(x + (size_t)(row0 + m)*DIN + kt*16 + g*8);
    float4 v0 = xr[0];
    float4 v1 = xr[1];
    float v[8] = {v0.x, v0.y, v0.z, v0.w, v1.x, v1.y, v1.z, v1.w};
    short8 hi, lo;
    #pragma unroll
    for (int i = 0; i < 8; ++i) {
      short h = f2bf(v[i]);
      hi[i] = h;
      lo[i] = f2bf(v[i] - bf2f(h));
    }
    const int base = (kt*64 + l)*8;
    *(short8*)&A1h[base] = hi;
    *(short8*)&A1l[base] = lo;
  }
  __syncthreads();
  {
    f32x16 c0 = fzero(), c1 = fzero();
    constexpr int ISTR = NTH*64*16;
    const short* bI = PIN + ((size_t)(2*w*64 + l))*16;
    short8 da0 = *(const short8*)(bI);
    short8 da1 = *(const short8*)(bI + 8);
    short8 da2 = *(const short8*)(bI + 1024);
    short8 da3 = *(const short8*)(bI + 1032);
    short8 db0, db1, db2, db3;
    #pragma unroll 1
    for (int kt = 0; kt < KTX; kt += 2) {
      short8 bh0 = *(const short8*)&A1h[(kt*64 + l)*8];
      short8 bl0 = *(const short8*)&A1l[(kt*64 + l)*8];
      {
        const short* p = bI + (size_t)(kt + 1)*ISTR;
        db0 = *(const short8*)(p);
        db1 = *(const short8*)(p + 8);
        db2 = *(const short8*)(p + 1024);
        db3 = *(const short8*)(p + 1032);
      }
      c0 = MF(da0, bh0, c0); c0 = MF(da1, bh0, c0); c0 = MF(da0, bl0, c0);
      c1 = MF(da2, bh0, c1); c1 = MF(da3, bh0, c1); c1 = MF(da2, bl0, c1);
      short8 bh1 = *(const short8*)&A1h[((kt+1)*64 + l)*8];
      short8 bl1 = *(const short8*)&A1l[((kt+1)*64 + l)*8];
      if (kt + 2 < KTX) {
        const short* p = bI + (size_t)(kt + 2)*ISTR;
        da0 = *(const short8*)(p);
        da1 = *(const short8*)(p + 8);
        da2 = *(const short8*)(p + 1024);
        da3 = *(const short8*)(p + 1032);
      }
      c0 = MF(db0, bh1, c0); c0 = MF(db1, bh1, c0); c0 = MF(db0, bl1, c0);
      c1 = MF(db2, bh1, c1); c1 = MF(db3, bh1, c1); c1 = MF(db2, bl1, c1);
    }
    #pragma unroll
    for (int s = 0; s < 32; ++s) {
      const int r = s & 15;
      const int cc = w*64 + (s >> 4)*32 + (r & 3) + ((r >> 2) << 3) + (g << 2);
      float v = (s < 16 ? c0[r] : c1[r]) + b_in[cc];
      cb[s] = v;
      xp[(size_t)(wg*8 + w)*2048 + s*64 + l] = v;
      zH[s] = H_init[cc];
      zL[s] = L_init[cc];
    }
  }
  __syncthreads();

  #pragma unroll 1
  for (int k = 0; k < 4; ++k) {
    #pragma unroll 1
    for (int hc = 0; hc < 2; ++hc) {
      #pragma unroll 1
      for (int li = 0; li < 3; ++li) {
        #pragma unroll
        for (int s = 0; s < 32; ++s) zL[s] += zH[s] + cb[s];
        sublayer(zL, P1, PD1, A1h, A1l, INh, INl, rmsS, w, l);
        sublayer(zL, P2, PD2, A1h, A1l, INh, INl, rmsS, w, l);
      }
      #pragma unroll
      for (int s = 0; s < 32; ++s) zH[s] += zL[s];
      sublayer(zH, P1, PD1, A1h, A1l, INh, INl, rmsS, w, l);
      sublayer(zH, P2, PD2, A1h, A1l, INh, INl, rmsS, w, l);
    }
    // ================= k-epilogue: logits / softmax / feedback =================
    {
      float part[10];
      #pragma unroll
      for (int c = 0; c < NC; ++c) part[c] = 0.f;
      #pragma unroll
      for (int s = 0; s < 32; ++s) {
        const int r = s & 15;
        const int cc = w*64 + (s >> 4)*32 + (r & 3) + ((r >> 2) << 3) + (g << 2);
        const float zz = zH[s];
        #pragma unroll
        for (int c = 0; c < NC; ++c) part[c] += zz * W_out[cc*NC + c];
      }
      #pragma unroll
      for (int c = 0; c < NC; ++c) part[c] += __shfl_xor(part[c], 32);
      if (l < 32) {
        #pragma unroll
        for (int c = 0; c < NC; ++c) lgS[(w*32 + l)*NC + c] = part[c];
      }
      __syncthreads();
      if (w == 0 && l < 32) {
        float lg[10];
        #pragma unroll
        for (int c = 0; c < NC; ++c) lg[c] = b_out[c];
        #pragma unroll
        for (int wv = 0; wv < 8; ++wv) {
          #pragma unroll
          for (int c = 0; c < NC; ++c) lg[c] += lgS[(wv*32 + l)*NC + c];
        }
        const int row = row0 + l;
        #pragma unroll
        for (int c = 0; c < NC; ++c) out[(size_t)(1 + k)*81920 + row*NC + c] = lg[c];
        if (k == 3) {
          #pragma unroll
          for (int c = 0; c < NC; ++c) out[row*NC + c] = lg[c];
        }
        float mx = lg[0];
        #pragma unroll
        for (int c = 1; c < NC; ++c) mx = fmaxf(mx, lg[c]);
        float e[10], sum = 0.f;
        #pragma unroll
        for (int c = 0; c < NC; ++c) { e[c] = __expf(lg[c] - mx); sum += e[c]; }
        const float inv = 1.0f / sum;
        #pragma unroll
        for (int c = 0; c < NC; ++c) pbS[l*NC + c] = e[c] * inv;
      }
      __syncthreads();
      if (k < 3) {
        #pragma unroll
        for (int s = 0; s < 32; ++s) {
          const int r = s & 15;
          const int cc = w*64 + (s >> 4)*32 + (r & 3) + ((r >> 2) << 3) + (g << 2);
          float fb = b_fb[cc];
          #pragma unroll
          for (int c = 0; c < NC; ++c) fb += pbS[m*NC + c] * W_fb[c*HD + cc];
          cb[s] = xp[(size_t)(wg*8 + w)*2048 + s*64 + l] + fb;
        }
      }
      __syncthreads();   // protect lgS/pbS (A1 alias) before next A1 staging
    }
  }
}

// ===================== weight preprocessing (packed layouts) =====================
__global__ void prep_gu(const float* __restrict__ Wgu, short* __restrict__ P)
{
  const int t = blockIdx.x*256 + threadIdx.x;
  if (t >= KT1*NP*64) return;
  const int l = t & 63;
  const int rest = t >> 6;
  const int nt = rest % NP;
  const int kt = rest / NP;
  const int n  = nt*32 + (l & 31);
  const int kb = kt*16 + (l >> 5)*8;
  short8 gh8, gl8, uh8, ul8;
  #pragma unroll
  for (int i = 0; i < 8; ++i) {
    float gv = 0.f, uv = 0.f;
    if (n < 682) {
      gv = Wgu[(size_t)(kb + i)*1364 + n];
      uv = Wgu[(size_t)(kb + i)*1364 + 682 + n];
    }
    short gh = f2bf(gv); gh8[i] = gh; gl8[i] = f2bf(gv - bf2f(gh));
    short uh = f2bf(uv); uh8[i] = uh; ul8[i] = f2bf(uv - bf2f(uh));
  }
  short* dst = P + ((size_t)(kt*NP + nt)*64 + l)*32;
  *(short8*)(dst)      = gh8;
  *(short8*)(dst + 8)  = gl8;
  *(short8*)(dst + 16) = uh8;
  *(short8*)(dst + 24) = ul8;
}

__global__ void prep_d(const float* __restrict__ Wd, short* __restrict__ P)
{
  const int t = blockIdx.x*256 + threadIdx.x;
  if (t >= KT2*NTH*64) return;
  const int l = t & 63;
  const int rest = t >> 6;
  const int nt = rest % NTH;
  const int kt2 = rest / NTH;
  const int n  = nt*32 + (l & 31);
  const int kb = kt2*16 + (l >> 5)*8;
  short8 h8, l8;
  #pragma unroll
  for (int i = 0; i < 8; ++i) {
    const int k2 = kb + i;
    float v = (k2 < 682) ? Wd[(size_t)k2*HD + n] : 0.f;
    short h = f2bf(v); h8[i] = h; l8[i] = f2bf(v - bf2f(h));
  }
  short* dst = P + ((size_t)(kt2*NTH + nt)*64 + l)*16;
  *(short8*)(dst)     = h8;
  *(short8*)(dst + 8) = l8;
}

__global__ void prep_in(const float* __restrict__ Win, short* __restrict__ P)
{
  const int t = blockIdx.x*256 + threadIdx.x;
  if (t >= KTX*NTH*64) return;
  const int l = t & 63;
  const int rest = t >> 6;
  const int nt = rest % NTH;
  const int kt = rest / NTH;
  const int n  = nt*32 + (l & 31);
  const int kb = kt*16 + (l >> 5)*8;
  short8 h8, l8;
  #pragma unroll
  for (int i = 0; i < 8; ++i) {
    float v = Win[(size_t)(kb + i)*HD + n];
    short h = f2bf(v); h8[i] = h; l8[i] = f2bf(v - bf2f(h));
  }
  short* dst = P + ((size_t)(kt*NTH + nt)*64 + l)*16;
  *(short8*)(dst)     = h8;
  *(short8*)(dst + 8) = l8;
}

extern "C" void kernel_launch(void* const* d_in, const int* in_sizes, int n_in,
                              void* d_out, int out_size, void* d_ws, size_t ws_size,
                              hipStream_t stream)
{
  const float* x     = (const float*)d_in[0];
  const float* W_in  = (const float*)d_in[1];
  const float* b_in  = (const float*)d_in[2];
  const float* W_fb  = (const float*)d_in[3];
  const float* b_fb  = (const float*)d_in[4];
  const float* Wgu1  = (const float*)d_in[5];
  const float* Wd1   = (const float*)d_in[6];
  const float* Wgu2  = (const float*)d_in[7];
  const float* Wd2   = (const float*)d_in[8];
  const float* Hini  = (const float*)d_in[9];
  const float* Lini  = (const float*)d_in[10];
  const float* W_out = (const float*)d_in[11];
  const float* b_out = (const float*)d_in[12];
  float* out = (float*)d_out;

  char* ws = (char*)d_ws;
  size_t off = 0;
  auto alloc = [&](size_t bytes) {
    char* p = ws + off;
    off = (off + bytes + 255) & ~(size_t)255;
    return p;
  };
  float* xp  = (float*)alloc((size_t)NROW*HD*4);
  short* PIN = (short*)alloc((size_t)SZ_PIN*2);
  short* P1  = (short*)alloc((size_t)SZ_P1*2);
  short* PD1 = (short*)alloc((size_t)SZ_PD*2);
  short* P2  = (short*)alloc((size_t)SZ_P1*2);
  short* PD2 = (short*)alloc((size_t)SZ_PD*2);

  const int n1 = KT1*NP*64;
  prep_gu<<<(n1+255)/256, 256, 0, stream>>>(Wgu1, P1);
  prep_gu<<<(n1+255)/256, 256, 0, stream>>>(Wgu2, P2);
  const int n2 = KT2*NTH*64;
  prep_d<<<(n2+255)/256, 256, 0, stream>>>(Wd1, PD1);
  prep_d<<<(n2+255)/256, 256, 0, stream>>>(Wd2, PD2);
  const int n3 = KTX*NTH*64;
  prep_in<<<(n3+255)/256, 256, 0, stream>>>(W_in, PIN);

  trm_main<<<256, 512, 0, stream>>>(x, b_in, W_fb, b_fb, Hini, Lini, W_out, b_out,
      xp, PIN, P1, PD1, P2, PD2, out);
}